// Round 10
// baseline (79.430 us; speedup 1.0000x reference)
//
#include <hip/hip_runtime.h>

typedef __bf16 bf16;
typedef __attribute__((ext_vector_type(4))) __bf16 bf16x4;
typedef __attribute__((ext_vector_type(8))) __bf16 bf16x8;
typedef __attribute__((ext_vector_type(4))) float f32x4;
typedef unsigned int u32;

#define MFMA16(a, b, c) __builtin_amdgcn_mfma_f32_16x16x32_bf16((a), (b), (c), 0, 0, 0)
#define LOG2E 1.4426950408889634f
#define AS1 __attribute__((address_space(1)))
#define AS3 __attribute__((address_space(3)))
#define GLL16(g, l) __builtin_amdgcn_global_load_lds((const AS1 u32*)(g), (AS3 u32*)(l), 16, 0, 0)

// KV chunk layout, per (b, kt=0..31): 20480 bytes =
//   [0,4096):     K tile [32 rows][64 o] bf16 (128B rows), blk swizzle ^(row&7)
//                 image row i holds K kv-row rotl5(i,1)  (proj stores at rotr)
//                 => lane's S D-elems are P[px][8u+2r+qt] -> pb0 contiguous octet
//   [4096,20480): V tile [256 c][32 q] bf16 (64B rows), blk swizzle ^(c&3)
// Pre-swizzled in GLOBAL so attn stages a LINEAR image via global_load_lds.

// ---------------------------------------------------------------------------
// Kernel 1: fused V-convert + W prep.
// ---------------------------------------------------------------------------
__global__ __launch_bounds__(256) void vprep_kernel(const float* __restrict__ kf,
                                                    const float* __restrict__ Wq,
                                                    const float* __restrict__ Wk,
                                                    const int* __restrict__ flag,
                                                    bf16* __restrict__ KV,
                                                    bf16* __restrict__ Wbh,
                                                    bf16* __restrict__ Wbl) {
  const int bid = blockIdx.x, t = threadIdx.x;
  if (bid < 4096) {
    int i = (bid << 8) + t;  // (b, c, q8)
    int q8 = i & 127, c = (i >> 7) & 255, b = i >> 15;
    const float* src = kf + ((size_t)(((b << 8) + c)) << 10) + (q8 << 3);
    float4 f0 = *(const float4*)src;
    float4 f1 = *(const float4*)(src + 4);
    bf16x8 v;
    v[0] = (bf16)f0.x; v[1] = (bf16)f0.y; v[2] = (bf16)f0.z; v[3] = (bf16)f0.w;
    v[4] = (bf16)f1.x; v[5] = (bf16)f1.y; v[6] = (bf16)f1.z; v[7] = (bf16)f1.w;
    int kt = q8 >> 2, qb = q8 & 3;
    char* dst = (char*)KV + (size_t)((b << 5) + kt) * 20480 + 4096 + c * 64 +
                16 * (qb ^ (c & 3));
    *(bf16x8*)dst = v;
  } else {
    int bx = bid - 4096;  // 0..31
    int z = bx >> 4;
    const float* src = (z == 0) ? Wq : ((flag[0] != 0) ? Wq : Wk);
    const float sc = (z == 0) ? LOG2E : 1.0f;  // exp2-domain softmax
    int i = ((((bx & 15) << 8) + t) << 2);
    float4 vv = *(const float4*)(src + i);
    vv.x *= sc; vv.y *= sc; vv.z *= sc; vv.w *= sc;
    bf16x4 hi, lo;
    hi[0] = (bf16)vv.x; lo[0] = (bf16)(vv.x - (float)hi[0]);
    hi[1] = (bf16)vv.y; lo[1] = (bf16)(vv.y - (float)hi[1]);
    hi[2] = (bf16)vv.z; lo[2] = (bf16)(vv.z - (float)hi[2]);
    hi[3] = (bf16)vv.w; lo[3] = (bf16)(vv.w - (float)hi[3]);
    *(bf16x4*)(Wbh + (z << 14) + i) = hi;
    *(bf16x4*)(Wbl + (z << 14) + i) = lo;
  }
}

// ---------------------------------------------------------------------------
// Kernel 2: MFMA projection. z=0 -> Qp (log2e-scaled); z=1 -> KV K-part,
// rho-permuted rows + swizzle. z=1 B-frags read bf16 from packed KV V-region.
// ---------------------------------------------------------------------------
__global__ __launch_bounds__(256) void proj_kernel(const float* __restrict__ qf,
                                                   const bf16* __restrict__ Wbh,
                                                   const bf16* __restrict__ Wbl,
                                                   const float* __restrict__ bq,
                                                   const float* __restrict__ bk,
                                                   const int* __restrict__ flag,
                                                   bf16* __restrict__ Qp,
                                                   bf16* __restrict__ KV) {
  const int b = blockIdx.y, z = blockIdx.z;
  const bf16* Wh = Wbh + z * 16384;
  const bf16* Wl = Wbl + z * 16384;
  const float* bias = z ? (flag[0] ? bq : bk) : bq;

  const int t = threadIdx.x;
  const int w = t >> 6, lane = t & 63;
  const int g = lane >> 4, l16 = lane & 15;
  const int wo = w >> 1, wp = w & 1;
  const int o0 = wo << 5;
  const int pbase = (blockIdx.x << 7) + (wp << 6);

  f32x4 acc[2][4];
#pragma unroll
  for (int ot = 0; ot < 2; ++ot) {
    float4 bv = *(const float4*)(bias + o0 + (ot << 4) + (g << 2));
    if (z == 0) { bv.x *= LOG2E; bv.y *= LOG2E; bv.z *= LOG2E; bv.w *= LOG2E; }
#pragma unroll
    for (int pt = 0; pt < 4; ++pt) acc[ot][pt] = (f32x4){bv.x, bv.y, bv.z, bv.w};
  }

  const float* xb = qf + ((((b << 8) + (g << 3)) << 10) + pbase + l16);
  const bf16* whb = Wh + ((o0 + l16) << 8) + (g << 3);
  const bf16* wlb = Wl + ((o0 + l16) << 8) + (g << 3);

  for (int kk = 0; kk < 8; ++kk) {
    bf16x8 ah[2], al[2];
#pragma unroll
    for (int ot = 0; ot < 2; ++ot) {
      ah[ot] = *(const bf16x8*)(whb + (ot << 12) + (kk << 5));
      al[ot] = *(const bf16x8*)(wlb + (ot << 12) + (kk << 5));
    }
#pragma unroll
    for (int pt = 0; pt < 4; ++pt) {
      bf16x8 xf;
      if (z == 0) {
        const float* xk = xb + (kk << 15);
        float xv[8];
#pragma unroll
        for (int j = 0; j < 8; ++j) xv[j] = xk[(j << 10) + (pt << 4)];
#pragma unroll
        for (int j = 0; j < 8; ++j) xf[j] = (bf16)xv[j];
      } else {
        // p = pbase + pt*16 + l16 ; c = kk*32 + 8g + j
        const int ktv = (pbase >> 5) + (pt >> 1);
        const int qb3 = ((pt & 1) << 1) + (l16 >> 3);
        const char* vp = (const char*)KV + (size_t)((b << 5) + ktv) * 20480 +
                         4096 + (((kk << 5) + (g << 3)) << 6) + ((l16 & 7) << 1);
#pragma unroll
        for (int j = 0; j < 8; ++j)
          xf[j] = *(const bf16*)(vp + (j << 6) + ((qb3 ^ (j & 3)) << 4));
      }
#pragma unroll
      for (int ot = 0; ot < 2; ++ot) {
        acc[ot][pt] = MFMA16(ah[ot], xf, acc[ot][pt]);
        acc[ot][pt] = MFMA16(al[ot], xf, acc[ot][pt]);
      }
    }
  }

#pragma unroll
  for (int ot = 0; ot < 2; ++ot)
#pragma unroll
    for (int pt = 0; pt < 4; ++pt) {
      bf16x4 q4;
#pragma unroll
      for (int r = 0; r < 4; ++r) q4[r] = (bf16)acc[ot][pt][r];
      int p = pbase + (pt << 4) + l16;
      if (z == 0) {
        *(bf16x4*)(Qp + ((((b << 10) + p)) << 6) + o0 + (ot << 4) + (g << 2)) = q4;
      } else {
        int kt = p >> 5, x = p & 31;
        int irow = (x >> 1) | ((x & 1) << 4);  // rotr5(x,1): image row
        int blk = (o0 >> 3) + (ot << 1) + (g >> 1);
        char* dst = (char*)KV + (size_t)((b << 5) + kt) * 20480 + irow * 128 +
                    16 * (blk ^ (irow & 7)) + ((g & 1) << 3);
        *(bf16x4*)dst = q4;
      }
    }
}

// ---------------------------------------------------------------------------
// Kernel 3: fused flash attention, channel-split PV + single softmax via
// in-lane P sharing. grid 512 (XCD-swz) x 256 thr (4 waves).
// Wave w: S+softmax for px [p0+16w,+16) (8 exp2/iter), publishes P as ONE
// b128/lane (rho payoff); after barrier PV for channels [64w,+64) using
// P of all 64 px. KVBLK=32, 32 iters, gll double-buffer (2x20KB),
// GLL issued post-P-barrier so drain hides under PV. 2 barriers/iter.
// ---------------------------------------------------------------------------
__global__ __launch_bounds__(256, 2) void attn_kernel(const bf16* __restrict__ KV,
                                                      const bf16* __restrict__ Qp,
                                                      float* __restrict__ out) {
  const int bid = blockIdx.x;
  const int wkid = ((bid & 7) << 6) + (bid >> 3);  // bijective: 512 % 8 == 0
  const int b = wkid >> 4, ptile = wkid & 15;
  const int p0 = ptile << 6;
  const int t = threadIdx.x;
  const int w = t >> 6, lane = t & 63;
  const int u = lane >> 4, l16 = lane & 15;

  __shared__ __align__(16) unsigned char smem[2][20480];
  __shared__ __align__(16) unsigned char sP[4096];  // [64 px][32 kv] bf16, swz
  __shared__ float sSc[64];
  __shared__ float sL[64];

  // Q B-fragments for this wave's 16 px (col=px, k=o)
  const bf16* qb = Qp + (((size_t)((b << 10) + p0 + (w << 4) + l16)) << 6) + (u << 3);
  const bf16x8 qa0 = *(const bf16x8*)qb;
  const bf16x8 qa1 = *(const bf16x8*)(qb + 32);

  const char* chunk0 = (const char*)KV + (size_t)b * (32 * 20480);

  f32x4 acc[4][4];  // [pg][ct]: c = 64w + 16ct + 4u + r, px = 16pg + l16
#pragma unroll
  for (int i = 0; i < 4; ++i)
#pragma unroll
    for (int j = 0; j < 4; ++j) acc[i][j] = (f32x4){0.f, 0.f, 0.f, 0.f};
  float m_ = -1e30f, l_ = 0.f;

  // P LDS offsets (write own row, read all 4 pg rows; 64B rows, swz ^(row&3))
  const int prow_w = (w << 4) + l16;
  const int pw_off = prow_w * 64 + 16 * (u ^ (prow_w & 3));

  // ---- stage tile 0 (4 waves x 5 x 16B x 64 lanes = 20480) ----
  {
    const char* g = chunk0 + w * 5120 + (lane << 4);
    unsigned char* l = smem[0] + w * 5120;
#pragma unroll
    for (int op = 0; op < 5; ++op) GLL16(g + op * 1024, l + op * 1024);
  }
  asm volatile("s_waitcnt vmcnt(0)" ::: "memory");
  __syncthreads();

  int cur = 0;
  for (int kt = 0; kt < 32; ++kt) {
    const unsigned char* sK = smem[cur];
    const unsigned char* sV = smem[cur] + 4096;

    // ---- S^T: 2 kv-tiles x 2 k-halves (rho-permuted K rows) ----
    f32x4 s[2];
#pragma unroll
    for (int qt = 0; qt < 2; ++qt) {
      const int R = (qt << 4) + l16;
      const int rb = R * 128;
      bf16x8 k0 = *(const bf16x8*)(sK + rb + 16 * (u ^ (R & 7)));
      bf16x8 k1 = *(const bf16x8*)(sK + rb + 16 * ((u + 4) ^ (R & 7)));
      f32x4 z = (f32x4){0.f, 0.f, 0.f, 0.f};
      z = MFMA16(k0, qa0, z);
      s[qt] = MFMA16(k1, qa1, z);
    }
    // ---- softmax (exp2 domain): 8 in-lane vals + 2 shfl, defer-max ----
    float tm = fmaxf(fmaxf(fmaxf(s[0][0], s[0][1]), fmaxf(s[0][2], s[0][3])),
                     fmaxf(fmaxf(s[1][0], s[1][1]), fmaxf(s[1][2], s[1][3])));
    tm = fmaxf(tm, __shfl_xor(tm, 16));
    tm = fmaxf(tm, __shfl_xor(tm, 32));
    float mn = fmaxf(m_, tm);
    if (mn - m_ <= 11.54f) mn = m_;  // defer: P bounded by 2^11.54 = e^8
    float sc = exp2f(m_ - mn);       // exactly 1.0 when deferred
    m_ = mn;
#pragma unroll
    for (int qt = 0; qt < 2; ++qt)
#pragma unroll
      for (int r = 0; r < 4; ++r) s[qt][r] = exp2f(s[qt][r] - m_);
    float rs = ((s[0][0] + s[0][1]) + (s[0][2] + s[0][3])) +
               ((s[1][0] + s[1][1]) + (s[1][2] + s[1][3]));
    rs += __shfl_xor(rs, 16);
    rs += __shfl_xor(rs, 32);
    l_ = l_ * sc + rs;
    // ---- P -> bf16 octet, publish (rho payoff: contiguous kv [8u,8u+8)) ----
    bf16x8 pb0;
#pragma unroll
    for (int r = 0; r < 4; ++r) {
      pb0[2 * r] = (bf16)s[0][r];
      pb0[2 * r + 1] = (bf16)s[1][r];
    }
    *(bf16x8*)(sP + pw_off) = pb0;
    if (lane < 16) sSc[(w << 4) + lane] = sc;
    __syncthreads();  // (1) P + sc visible

    // ---- issue next chunk's GLL now (drains at iter-end barrier) ----
    if (kt < 31) {
      const char* g = chunk0 + (kt + 1) * 20480 + w * 5120 + (lane << 4);
      unsigned char* l = smem[cur ^ 1] + w * 5120;
#pragma unroll
      for (int op = 0; op < 5; ++op) GLL16(g + op * 1024, l + op * 1024);
    }
    // ---- conditional acc rescale (cols = px(pg,l16)) ----
    float scv[4];
#pragma unroll
    for (int pg = 0; pg < 4; ++pg) scv[pg] = sSc[(pg << 4) + l16];
    if (__any((scv[0] != 1.f) || (scv[1] != 1.f) || (scv[2] != 1.f) || (scv[3] != 1.f))) {
#pragma unroll
      for (int pg = 0; pg < 4; ++pg)
#pragma unroll
        for (int ct = 0; ct < 4; ++ct) {
          acc[pg][ct][0] *= scv[pg]; acc[pg][ct][1] *= scv[pg];
          acc[pg][ct][2] *= scv[pg]; acc[pg][ct][3] *= scv[pg];
        }
    }
    // ---- PV: 4 P-frags (all px) x 4 V-frags (own 64 ch) -> 16 mfma ----
    bf16x8 pbr[4];
#pragma unroll
    for (int pg = 0; pg < 4; ++pg) {
      const int rr = (pg << 4) + l16;
      pbr[pg] = *(const bf16x8*)(sP + rr * 64 + 16 * (u ^ (rr & 3)));
    }
#pragma unroll
    for (int ct = 0; ct < 4; ++ct) {
      const int cr = (w << 6) + (ct << 4) + l16;
      bf16x8 va = *(const bf16x8*)(sV + cr * 64 + 16 * (u ^ (cr & 3)));
#pragma unroll
      for (int pg = 0; pg < 4; ++pg) acc[pg][ct] = MFMA16(va, pbr[pg], acc[pg][ct]);
    }
    asm volatile("s_waitcnt vmcnt(0)" ::: "memory");
    __syncthreads();  // (2) next chunk landed; P/KV reads done
    cur ^= 1;
  }

  // ---- epilogue: share l, per-lane normalize, direct stores ----
  if (lane < 16) sL[(w << 4) + lane] = l_;
  __syncthreads();
#pragma unroll
  for (int pg = 0; pg < 4; ++pg) {
    const float inv = 1.f / sL[(pg << 4) + l16];
    float* ob = out + ((size_t)b << 18) + p0 + (pg << 4) + l16;
#pragma unroll
    for (int ct = 0; ct < 4; ++ct)
#pragma unroll
      for (int r = 0; r < 4; ++r) {
        int c = (w << 6) + (ct << 4) + (u << 2) + r;
        ob[(size_t)c << 10] = acc[pg][ct][r] * inv;
      }
  }
}

// ---------------------------------------------------------------------------
extern "C" void kernel_launch(void* const* d_in, const int* in_sizes, int n_in,
                              void* d_out, int out_size, void* d_ws, size_t ws_size,
                              hipStream_t stream) {
  const float* qf = (const float*)d_in[0];
  const float* kf = (const float*)d_in[1];
  const float* Wq = (const float*)d_in[2];
  const float* bq = (const float*)d_in[3];
  const float* Wk = (const float*)d_in[4];
  const float* bk = (const float*)d_in[5];
  // d_in[6] = vis_CA (unused)
  const int* flag = (const int*)d_in[7];  // same_WqWk
  float* out = (float*)d_out;

  char* ws = (char*)d_ws;
  bf16* Qp = (bf16*)ws;                          // 4 MiB: [32][1024][64] bf16
  bf16* Wbh = (bf16*)(ws + (4u << 20));          // 64 KiB
  bf16* Wbl = (bf16*)(ws + (4u << 20) + 65536);  // 64 KiB
  bf16* KV = (bf16*)(ws + (5u << 20));           // 20 MiB: [32][32] x 20480B chunks

  vprep_kernel<<<4128, 256, 0, stream>>>(kf, Wq, Wk, flag, KV, Wbh, Wbl);
  proj_kernel<<<dim3(8, 32, 2), 256, 0, stream>>>(qf, Wbh, Wbl, bq, bk, flag, Qp, KV);
  attn_kernel<<<512, 256, 0, stream>>>(KV, Qp, out);
}